// Round 5
// 2075.779 us; speedup vs baseline: 1.2711x; 1.2711x over previous
//
#include <hip/hip_runtime.h>
#include <hip/hip_cooperative_groups.h>

typedef short v8s __attribute__((ext_vector_type(8)));
typedef float v4f __attribute__((ext_vector_type(4)));
typedef unsigned short ushort_t;
typedef unsigned int uint_t;

namespace cg = cooperative_groups;

// ---------- helpers ----------
__device__ inline ushort_t f2bf(float f) {
    union { float f; uint_t u; } v; v.f = f;
    uint_t r = v.u + 0x7FFFu + ((v.u >> 16) & 1u);   // RNE
    return (ushort_t)(r >> 16);
}
__device__ inline float bf2f(ushort_t h) {
    union { uint_t u; float f; } v; v.u = ((uint_t)h) << 16;
    return v.f;
}
__device__ inline float sigf(float x) { return 1.f / (1.f + __expf(-x)); }
__device__ inline float tanh_f(float x) {
    float e = __expf(-2.f * x);
    return (1.f - e) / (1.f + e);
}

// ---------- lengths ----------
__global__ void k_lens(const int* __restrict__ tc, const int* __restrict__ uh,
                       int* lens_s, int* lens_h, int* lens_c) {
    int t = blockIdx.x * 256 + threadIdx.x;
    if (t < 640) {
        int c = 0;
        for (int s = 0; s < 50; ++s) c += (tc[t * 53 + 3 + s] != 0);
        lens_s[t] = c;
    } else if (t < 2240) {
        int r = t - 640; int c = 0;
        for (int s = 0; s < 50; ++s) c += (uh[r * 50 + s] != 0);
        lens_h[r] = c;
    } else if (t < 2272) {
        int b = t - 2240; int c = 0;
        for (int tt = 0; tt < 20; ++tt) c += (tc[(b * 20 + tt) * 53 + 3] != 0);
        lens_c[b] = c;
    }
}

// ---------- sort by length descending (brute-force rank, multi-block) ----------
__global__ void k_sort(const int* __restrict__ lens, int n,
                       int* __restrict__ perm, int* __restrict__ slen) {
    int i = blockIdx.x * 256 + threadIdx.x;
    if (i >= n) return;
    int li = lens[i]; int r = 0;
    for (int j = 0; j < n; ++j) {
        int lj = lens[j];
        r += (lj > li) || (lj == li && j < i);
    }
    perm[r] = i; slen[r] = li;
}

// ---------- pack A weights, gate-interleaved: n' = d*4 + gate ----------
// K layout: [0..299]=Wih, [300]=bih+bhh, [301..319]=0, [320..469]=Whh, [470..479]=0
__global__ void k_packA(const float* __restrict__ Wih, const float* __restrict__ Whh,
                        const float* __restrict__ bih, const float* __restrict__ bhh,
                        ushort_t* __restrict__ pack) {
    int job = blockIdx.x; int lane = threadIdx.x;
    int set = job / 570; int rem = job % 570; int tile = rem / 15; int kc = rem % 15;
    int np = tile * 16 + (lane & 15);
    int g = np & 3, d = np >> 2;
    int orig = g * 150 + d;
    int kbase = kc * 32 + (lane >> 4) * 8;
    ushort_t v[8];
#pragma unroll
    for (int j = 0; j < 8; ++j) {
        int k = kbase + j; float f = 0.f;
        if (np < 600) {
            if (k < 300) f = Wih[((size_t)set * 600 + orig) * 300 + k];
            else if (k == 300) f = bih[set * 600 + orig] + bhh[set * 600 + orig];
            else if (k >= 320 && k < 470) f = Whh[((size_t)set * 600 + orig) * 150 + (k - 320)];
        }
        v[j] = f2bf(f);
    }
    uint4 u;
    u.x = (uint_t)v[0] | ((uint_t)v[1] << 16);
    u.y = (uint_t)v[2] | ((uint_t)v[3] << 16);
    u.z = (uint_t)v[4] | ((uint_t)v[5] << 16);
    u.w = (uint_t)v[6] | ((uint_t)v[7] << 16);
    *(uint4*)(pack + ((size_t)job * 64 + lane) * 8) = u;
}

// ---------- pack C weights (Din=303, bias at k=303) ----------
__global__ void k_packC(const float* __restrict__ Wih, const float* __restrict__ Whh,
                        const float* __restrict__ bih, const float* __restrict__ bhh,
                        ushort_t* __restrict__ pack) {
    int job = blockIdx.x; int lane = threadIdx.x;
    int dir = job / 570; int rem = job % 570; int tile = rem / 15; int kc = rem % 15;
    int np = tile * 16 + (lane & 15);
    int g = np & 3, d = np >> 2;
    int orig = g * 150 + d;
    int kbase = kc * 32 + (lane >> 4) * 8;
    ushort_t v[8];
#pragma unroll
    for (int j = 0; j < 8; ++j) {
        int k = kbase + j; float f = 0.f;
        if (np < 600) {
            if (k < 303) f = Wih[((size_t)dir * 600 + orig) * 303 + k];
            else if (k == 303) f = bih[dir * 600 + orig] + bhh[dir * 600 + orig];
            else if (k >= 320 && k < 470) f = Whh[((size_t)dir * 600 + orig) * 150 + (k - 320)];
        }
        v[j] = f2bf(f);
    }
    uint4 u;
    u.x = (uint_t)v[0] | ((uint_t)v[1] << 16);
    u.y = (uint_t)v[2] | ((uint_t)v[3] << 16);
    u.z = (uint_t)v[4] | ((uint_t)v[5] << 16);
    u.w = (uint_t)v[6] | ((uint_t)v[7] << 16);
    *(uint4*)(pack + ((size_t)job * 64 + lane) * 8) = u;
}

// =====================================================================
// Persistent cooperative kernel: alternate [gx GEMM phase] / [rec phase]
// grid = 256 blocks x 256 threads, 1 block/CU  (round-0-proven config).
// grpjob/bid 0..169:  <20 -> s (2 dirs x 10 seqblks of 64), else h (6 x 25)
// gx arena layout: slot=grpjob: [lt<TC][tn<38][m<64][l16<16] ushort
// Rec phase streams Whh fragments + gate loads with one-j-ahead ping-pong
// prefetch (keeps live set < 256 VGPR -> no scratch spills in the serial
// loop; hides L3/HBM gate latency under the MFMA cluster).
// =====================================================================
__launch_bounds__(256, 1)
__global__ void k_main(const int* __restrict__ tcg, const int* __restrict__ uhg,
                       const float* __restrict__ E,
                       const int* __restrict__ perm_s, const int* __restrict__ slen_s,
                       const int* __restrict__ perm_h, const int* __restrict__ hlen_s,
                       const ushort_t* __restrict__ packA,
                       ushort_t* __restrict__ gx,
                       float* __restrict__ srep, float* __restrict__ reps,
                       int TC, int nchunks) {
    const int bid = blockIdx.x;
    const int tid = threadIdx.x;
    const int lane = tid & 63, w = tid >> 6, q = lane >> 4, l16 = lane & 15;

    __shared__ ushort_t H[64][168];
    __shared__ __align__(16) float Gp[4][16][68];

    // ---- rec-role decode (bid < 170) ----
    const int isrec = (bid < 170);
    int r_pos0 = 0, r_windex = 0, r_dir = 0;
    const int* r_lenv = slen_s; const int* r_permv = perm_s;
    float* r_outp = srep;
    if (isrec) {
        if (bid < 20) {
            int grp = bid / 10; r_dir = grp; r_windex = grp; r_pos0 = (bid % 10) * 64;
            r_lenv = slen_s; r_permv = perm_s; r_outp = srep;
        } else {
            int gh = (bid - 20) / 25; r_windex = gh; r_dir = gh & 1;
            r_pos0 = ((bid - 20) % 25) * 64;
            r_lenv = hlen_s; r_permv = perm_h;
            r_outp = reps + (size_t)(gh >> 1) * 1600 * 300;
        }
        for (int i = tid; i < 64 * 84; i += 256) ((uint_t*)H)[i] = 0u;
    }
    int len4[4];
    if (isrec) {
#pragma unroll
        for (int i = 0; i < 4; ++i) len4[i] = r_lenv[r_pos0 + l16 + 16 * i];
    }
    float cst[10][4];
#pragma unroll
    for (int j = 0; j < 10; ++j)
#pragma unroll
        for (int i = 0; i < 4; ++i) cst[j][i] = 0.f;

    cg::grid_group grid = cg::this_grid();

    for (int c = 0; c < nchunks; ++c) {
        const int tcs0 = 50 - c * TC;
        const int tcs = tcs0 < TC ? tcs0 : TC;
        // ================= gx producer phase (round-0 verbatim) =================
        {
            const int nstepblk = (tcs + 3) / 4;
            const int njobs = 170 * nstepblk;
            for (int job = bid; job < njobs; job += 256) {
                int gj = job % 170; int sb = job / 170;
                const int* lenv; const int* permv; int pos0, windex, dir, isS;
                if (gj < 20) {
                    int grp = gj / 10; dir = grp; windex = grp; pos0 = (gj % 10) * 64;
                    lenv = slen_s; permv = perm_s; isS = 1;
                } else {
                    int gh = (gj - 20) / 25; windex = gh; dir = gh & 1;
                    pos0 = ((gj - 20) % 25) * 64;
                    lenv = hlen_s; permv = perm_h; isS = 0;
                }
                if (lenv[pos0] <= c * TC) continue;   // sorted desc => block dead
                int lt = sb * 4 + w;
                if (lt >= tcs) continue;              // wave-level, no barriers here
                int t = c * TC + lt;

                // ---- A fragments: direct E gather, fp32->bf16 ----
                v8s a[4][10];
#pragma unroll
                for (int mtg = 0; mtg < 4; ++mtg) {
                    int pos = pos0 + mtg * 16 + l16;
                    int len = lenv[pos];
                    int tau = dir ? (len - 1 - t) : t;
                    tau = tau < 0 ? 0 : (tau > 49 ? 49 : tau);
                    int orig = permv[pos];
                    int tok = isS ? tcg[orig * 53 + 3 + tau] : uhg[orig * 50 + tau];
                    const float* Er = E + (size_t)tok * 300;
#pragma unroll
                    for (int kc = 0; kc < 9; ++kc) {
                        int k0 = kc * 32 + q * 8;
                        float4 f0 = *(const float4*)(Er + k0);
                        float4 f1 = *(const float4*)(Er + k0 + 4);
                        v8s r;
                        r[0] = (short)f2bf(f0.x); r[1] = (short)f2bf(f0.y);
                        r[2] = (short)f2bf(f0.z); r[3] = (short)f2bf(f0.w);
                        r[4] = (short)f2bf(f1.x); r[5] = (short)f2bf(f1.y);
                        r[6] = (short)f2bf(f1.z); r[7] = (short)f2bf(f1.w);
                        a[mtg][kc] = r;
                    }
                    {   // kc = 9: k = 288 + q*8 + j ; col 300 = 1.0 (bias), >300 = 0
                        v8s r = (v8s){0,0,0,0,0,0,0,0};
                        if (q == 0) {
                            float4 f0 = *(const float4*)(Er + 288);
                            float4 f1 = *(const float4*)(Er + 292);
                            r[0] = (short)f2bf(f0.x); r[1] = (short)f2bf(f0.y);
                            r[2] = (short)f2bf(f0.z); r[3] = (short)f2bf(f0.w);
                            r[4] = (short)f2bf(f1.x); r[5] = (short)f2bf(f1.y);
                            r[6] = (short)f2bf(f1.z); r[7] = (short)f2bf(f1.w);
                        } else if (q == 1) {
                            float4 f0 = *(const float4*)(Er + 296);
                            r[0] = (short)f2bf(f0.x); r[1] = (short)f2bf(f0.y);
                            r[2] = (short)f2bf(f0.z); r[3] = (short)f2bf(f0.w);
                            r[4] = (short)0x3F80;   // bias multiplier 1.0
                        }
                        a[mtg][9] = r;
                    }
                }

                const ushort_t* W = packA + (size_t)windex * 570 * 512;
                ushort_t* gout = gx + ((size_t)gj * TC + lt) * 38 * 1024;

                v8s bA[10], bB[10];
                auto loadB = [&](v8s* dst, int tn) {
                    const ushort_t* p = W + (size_t)tn * 15 * 512 + lane * 8;
#pragma unroll
                    for (int kc = 0; kc < 10; ++kc) dst[kc] = *(const v8s*)(p + (size_t)kc * 512);
                };
                auto compute = [&](int tn, v8s* b) {
                    v4f acc[4];
#pragma unroll
                    for (int mtg = 0; mtg < 4; ++mtg) acc[mtg] = (v4f){0.f, 0.f, 0.f, 0.f};
#pragma unroll
                    for (int kc = 0; kc < 10; ++kc)
#pragma unroll
                        for (int mtg = 0; mtg < 4; ++mtg)
                            acc[mtg] = __builtin_amdgcn_mfma_f32_16x16x32_bf16(a[mtg][kc], b[kc], acc[mtg], 0, 0, 0);
                    ushort_t* gt = gout + tn * 1024 + l16;
#pragma unroll
                    for (int mtg = 0; mtg < 4; ++mtg)
#pragma unroll
                        for (int r = 0; r < 4; ++r)
                            gt[(mtg * 16 + q * 4 + r) * 16] = f2bf(acc[mtg][r]);
                };
                loadB(bA, 0);
                for (int tn = 0; tn < 38; tn += 2) {
                    loadB(bB, tn + 1 < 38 ? tn + 1 : 37);
                    compute(tn, bA);
                    loadB(bA, tn + 2 < 38 ? tn + 2 : 37);
                    compute(tn + 1, bB);
                }
            }
        }
        grid.sync();
        // ================= recurrence phase =================
        if (isrec) {
            int blockmax = r_lenv[r_pos0];
            int steps = blockmax - c * TC;
            steps = steps < 0 ? 0 : (steps > tcs ? tcs : steps);
            if (steps > 0) {
                const ushort_t* wslot = packA + (size_t)r_windex * 570 * 512;
                const ushort_t* gslot = gx + (size_t)bid * TC * 38 * 1024;
                // streamed Whh fragments (kc 10..14 of the pack), clamped tn
                auto loadW = [&](int j, v8s (&dst)[5]) {
                    int tn = w + 4 * j; int tnc = tn > 37 ? 37 : tn;
                    const ushort_t* wp = wslot + (size_t)tnc * 15 * 512 + lane * 8;
#pragma unroll
                    for (int kc = 0; kc < 5; ++kc) dst[kc] = *(const v8s*)(wp + (size_t)(10 + kc) * 512);
                };
                for (int lt = 0; lt < steps; ++lt) {
                    int t = c * TC + lt;
                    const ushort_t* gstep = gslot + (size_t)lt * 38 * 1024;
                    auto loadG = [&](int j, ushort4 (&dst)[4]) {
                        int tn = w + 4 * j; int tnc = tn > 37 ? 37 : tn;
                        const ushort_t* gb = gstep + (size_t)tnc * 1024 + q * 4;
#pragma unroll
                        for (int i = 0; i < 4; ++i)
                            dst[i] = *(const ushort4*)(gb + (l16 + 16 * i) * 16);
                    };
                    v8s wbA[5], wbB[5];
                    ushort4 gqA[4], gqB[4];
                    // issue j=0 loads before the barrier: independent of H
                    loadW(0, wbA); loadG(0, gqA);
                    __syncthreads();   // prior-step H writes visible
                    v8s ah[4][5];
#pragma unroll
                    for (int mtg = 0; mtg < 4; ++mtg)
#pragma unroll
                        for (int kc = 0; kc < 5; ++kc)
                            ah[mtg][kc] = *(const v8s*)&H[mtg * 16 + l16][kc * 32 + q * 8];
                    __syncthreads();   // ah loaded; H writable
                    auto jbody = [&](int j, v8s (&wcur)[5], ushort4 (&gcur)[4],
                                     v8s (&wnxt)[5], ushort4 (&gnxt)[4]) {
                        if (j < 9) { loadW(j + 1, wnxt); loadG(j + 1, gnxt); }
                        int tn = w + 4 * j;
                        if (tn < 38) {
                            v4f acc[4];
#pragma unroll
                            for (int mtg = 0; mtg < 4; ++mtg) acc[mtg] = (v4f){0.f, 0.f, 0.f, 0.f};
#pragma unroll
                            for (int kc = 0; kc < 5; ++kc)
#pragma unroll
                                for (int mtg = 0; mtg < 4; ++mtg)
                                    acc[mtg] = __builtin_amdgcn_mfma_f32_16x16x32_bf16(ah[mtg][kc], wcur[kc], acc[mtg], 0, 0, 0);
#pragma unroll
                            for (int mtg = 0; mtg < 4; ++mtg)
                                *(v4f*)&Gp[w][l16][mtg * 16 + q * 4] = acc[mtg];
                            int d = 4 * tn + q;
#pragma unroll
                            for (int i = 0; i < 4; ++i) {
                                int m = l16 + 16 * i;
                                if (t < len4[i]) {
                                    float gi = bf2f(gcur[i].x) + Gp[w][q * 4 + 0][m];
                                    float gf = bf2f(gcur[i].y) + Gp[w][q * 4 + 1][m];
                                    float gg = bf2f(gcur[i].z) + Gp[w][q * 4 + 2][m];
                                    float go = bf2f(gcur[i].w) + Gp[w][q * 4 + 3][m];
                                    float cn = sigf(gf) * cst[j][i] + sigf(gi) * tanh_f(gg);
                                    cst[j][i] = cn;
                                    if (d < 150) H[m][d] = f2bf(sigf(go) * tanh_f(cn));
                                }
                            }
                        }
                    };
                    jbody(0, wbA, gqA, wbB, gqB);
                    jbody(1, wbB, gqB, wbA, gqA);
                    jbody(2, wbA, gqA, wbB, gqB);
                    jbody(3, wbB, gqB, wbA, gqA);
                    jbody(4, wbA, gqA, wbB, gqB);
                    jbody(5, wbB, gqB, wbA, gqA);
                    jbody(6, wbA, gqA, wbB, gqB);
                    jbody(7, wbB, gqB, wbA, gqA);
                    jbody(8, wbA, gqA, wbB, gqB);
                    jbody(9, wbB, gqB, wbA, gqA);
                }
                __syncthreads();
            }
        }
        grid.sync();
    }
    // ---- final outputs ----
    if (isrec) {
        int m = tid >> 2, dc = tid & 3;
        int orig = r_permv[r_pos0 + m];
#pragma unroll
        for (int k = 0; k < 38; ++k) {
            int d = dc + 4 * k;
            if (d < 150) r_outp[(size_t)orig * 300 + r_dir * 150 + d] = bf2f(H[m][d]);
        }
    }
}

// ---------- C-LSTM x-projection GEMM (split over tn via blockIdx.z) ----------
// rows per dir: R = b*20 + t (consumption step t); A source te = dir? clen-1-t : t
// gxc layout: [dir][t][tn][b<32][l16<16] ushort
__launch_bounds__(256, 1)
__global__ void k_gxc(const float* __restrict__ srep, const int* __restrict__ tcg,
                      const int* __restrict__ lens_c, const ushort_t* __restrict__ packC,
                      ushort_t* __restrict__ gxc) {
    const int dir = blockIdx.y;
    const int R0 = blockIdx.x * 256;
    const int tnbase = blockIdx.z * 2;
    const int tid = threadIdx.x, lane = tid & 63, w = tid >> 6, q = lane >> 4, l16 = lane & 15;

    v8s a[4][10];
#pragma unroll
    for (int mtg = 0; mtg < 4; ++mtg) {
        int R = R0 + w * 64 + mtg * 16 + l16;
        R = R < 639 ? R : 639;
        int b = R / 20, t = R % 20;
        int clen = lens_c[b];
        int te = dir ? (clen - 1 - t) : t;
        te = te < 0 ? 0 : (te > 19 ? 19 : te);
        const float* sr = srep + (size_t)(b * 20 + te) * 300;
        const int* ft = tcg + (size_t)(b * 20 + te) * 53;
#pragma unroll
        for (int kc = 0; kc < 9; ++kc) {
            int k0 = kc * 32 + q * 8;
            float4 f0 = *(const float4*)(sr + k0);
            float4 f1 = *(const float4*)(sr + k0 + 4);
            v8s r;
            r[0] = (short)f2bf(f0.x); r[1] = (short)f2bf(f0.y);
            r[2] = (short)f2bf(f0.z); r[3] = (short)f2bf(f0.w);
            r[4] = (short)f2bf(f1.x); r[5] = (short)f2bf(f1.y);
            r[6] = (short)f2bf(f1.z); r[7] = (short)f2bf(f1.w);
            a[mtg][kc] = r;
        }
        {   // kc=9: k = 288+q*8+j; 300..302 = feats, 303 = 1.0
            v8s r = (v8s){0,0,0,0,0,0,0,0};
            if (q == 0) {
                float4 f0 = *(const float4*)(sr + 288);
                float4 f1 = *(const float4*)(sr + 292);
                r[0] = (short)f2bf(f0.x); r[1] = (short)f2bf(f0.y);
                r[2] = (short)f2bf(f0.z); r[3] = (short)f2bf(f0.w);
                r[4] = (short)f2bf(f1.x); r[5] = (short)f2bf(f1.y);
                r[6] = (short)f2bf(f1.z); r[7] = (short)f2bf(f1.w);
            } else if (q == 1) {
                float4 f0 = *(const float4*)(sr + 296);
                r[0] = (short)f2bf(f0.x); r[1] = (short)f2bf(f0.y);
                r[2] = (short)f2bf(f0.z); r[3] = (short)f2bf(f0.w);
                r[4] = (short)f2bf((float)ft[0]);
                r[5] = (short)f2bf((float)ft[1]);
                r[6] = (short)f2bf((float)ft[2]);
                r[7] = (short)0x3F80;
            }
            a[mtg][9] = r;
        }
    }
    const ushort_t* W = packC + (size_t)dir * 570 * 512;
    v8s bA[10];
    auto loadB = [&](v8s* dst, int tn) {
        const ushort_t* p = W + (size_t)tn * 15 * 512 + lane * 8;
#pragma unroll
        for (int kc = 0; kc < 10; ++kc) dst[kc] = *(const v8s*)(p + (size_t)kc * 512);
    };
    auto compute = [&](int tn, v8s* b) {
        v4f acc[4];
#pragma unroll
        for (int mtg = 0; mtg < 4; ++mtg) acc[mtg] = (v4f){0.f, 0.f, 0.f, 0.f};
#pragma unroll
        for (int kc = 0; kc < 10; ++kc)
#pragma unroll
            for (int mtg = 0; mtg < 4; ++mtg)
                acc[mtg] = __builtin_amdgcn_mfma_f32_16x16x32_bf16(a[mtg][kc], b[kc], acc[mtg], 0, 0, 0);
#pragma unroll
        for (int mtg = 0; mtg < 4; ++mtg)
#pragma unroll
            for (int r = 0; r < 4; ++r) {
                int R = R0 + w * 64 + mtg * 16 + q * 4 + r;
                if (R < 640) {
                    int b = R / 20, t = R % 20;
                    gxc[(((size_t)(dir * 20 + t) * 38 + tn) << 9) + b * 16 + l16] = f2bf(acc[mtg][r]);
                }
            }
    };
    for (int tn = tnbase; tn < tnbase + 2; ++tn) {
        loadB(bA, tn);
        compute(tn, bA);
    }
}

// ---------- conversation-level recurrence: register Whh, M=32 ----------
__launch_bounds__(256, 1)
__global__ void k_rec_c(const ushort_t* __restrict__ gxc, const int* __restrict__ lens_c,
                        const ushort_t* __restrict__ packC, float* __restrict__ out) {
    const int dir = blockIdx.x;
    const int tid = threadIdx.x, lane = tid & 63, w = tid >> 6, q = lane >> 4, l16 = lane & 15;

    __shared__ ushort_t H[32][168];
    __shared__ __align__(16) float Gp[4][16][68];
    __shared__ int lensl[32];
    __shared__ int mxs;

    if (tid < 32) lensl[tid] = lens_c[tid];
    for (int i = tid; i < 32 * 84; i += 256) ((uint_t*)H)[i] = 0u;
    __syncthreads();
    if (tid == 0) {
        int mx = 0;
        for (int i = 0; i < 32; ++i) mx = max(mx, lensl[i]);
        mxs = mx;
    }
    __syncthreads();
    const int maxlen = mxs;
    int len2[2];
#pragma unroll
    for (int i = 0; i < 2; ++i) len2[i] = lensl[i * 16 + l16];

    v8s wb[10][5];
#pragma unroll
    for (int j = 0; j < 10; ++j) {
        int tn = w + 4 * j; int tnc = tn > 37 ? 37 : tn;
        const ushort_t* wp = packC + (size_t)dir * 570 * 512 + (size_t)tnc * 15 * 512 + lane * 8;
#pragma unroll
        for (int kc = 0; kc < 5; ++kc) wb[j][kc] = *(const v8s*)(wp + (size_t)(10 + kc) * 512);
    }
    float cst[10][2];
#pragma unroll
    for (int j = 0; j < 10; ++j)
#pragma unroll
        for (int i = 0; i < 2; ++i) cst[j][i] = 0.f;

    for (int t = 0; t < maxlen; ++t) {
        __syncthreads();
        v8s ah[2][5];
#pragma unroll
        for (int mtg = 0; mtg < 2; ++mtg)
#pragma unroll
            for (int kc = 0; kc < 5; ++kc)
                ah[mtg][kc] = *(const v8s*)&H[mtg * 16 + l16][kc * 32 + q * 8];
        __syncthreads();
#pragma unroll
        for (int j = 0; j < 10; ++j) {
            int tn = w + 4 * j;
            if (tn < 38) {
                v4f acc[2];
#pragma unroll
                for (int mtg = 0; mtg < 2; ++mtg) acc[mtg] = (v4f){0.f, 0.f, 0.f, 0.f};
#pragma unroll
                for (int kc = 0; kc < 5; ++kc)
#pragma unroll
                    for (int mtg = 0; mtg < 2; ++mtg)
                        acc[mtg] = __builtin_amdgcn_mfma_f32_16x16x32_bf16(ah[mtg][kc], wb[j][kc], acc[mtg], 0, 0, 0);
#pragma unroll
                for (int mtg = 0; mtg < 2; ++mtg)
                    *(v4f*)&Gp[w][l16][mtg * 16 + q * 4] = acc[mtg];
                int d = 4 * tn + q;
                const ushort_t* gbase = gxc + (((size_t)(dir * 20 + t) * 38 + tn) << 9) + q * 4;
#pragma unroll
                for (int i = 0; i < 2; ++i) {
                    int m = l16 + 16 * i;
                    if (t < len2[i]) {
                        ushort4 gv = *(const ushort4*)(gbase + m * 16);
                        float gi = bf2f(gv.x) + Gp[w][q * 4 + 0][m];
                        float gf = bf2f(gv.y) + Gp[w][q * 4 + 1][m];
                        float gg = bf2f(gv.z) + Gp[w][q * 4 + 2][m];
                        float go = bf2f(gv.w) + Gp[w][q * 4 + 3][m];
                        float cn = sigf(gf) * cst[j][i] + sigf(gi) * tanh_f(gg);
                        cst[j][i] = cn;
                        if (d < 150) H[m][d] = f2bf(sigf(go) * tanh_f(cn));
                    }
                }
            }
        }
    }
    __syncthreads();
    {
        int m = tid >> 3;
#pragma unroll
        for (int k = 0; k < 19; ++k) {
            int d = (tid & 7) + 8 * k;
            if (d < 150) out[(size_t)m * 300 + dir * 150 + d] = bf2f(H[m][d]);
        }
    }
}

// ---------- attention hops + output ----------
__global__ void k_attn(const float* __restrict__ reps, const float* __restrict__ u_in,
                       const float* __restrict__ Wout, const float* __restrict__ bout,
                       float* __restrict__ out) {
    const int b = blockIdx.x;
    const int tid = threadIdx.x;
    const int wave = tid >> 6, lane = tid & 63;
    __shared__ float u_l[300];
    __shared__ float dots[64];
    __shared__ float red[4];
    for (int d = tid; d < 300; d += 256) u_l[d] = u_in[b * 300 + d];
    __syncthreads();
    for (int hop = 0; hop < 2; ++hop) {
        const float* R0 = reps + ((size_t)hop * 1600 + b * 50) * 300;
        for (int n = wave; n < 50; n += 4) {
            float p = 0.f;
            for (int d = lane; d < 300; d += 64) p += R0[(size_t)n * 300 + d] * u_l[d];
            for (int off = 32; off > 0; off >>= 1) p += __shfl_down(p, off);
            if (lane == 0) dots[n] = p;
        }
        __syncthreads();
        if (tid < 64) {
            float x = (lane < 50) ? dots[lane] : -3.4e38f;
            float mx = x;
            for (int off = 32; off > 0; off >>= 1) mx = fmaxf(mx, __shfl_down(mx, off));
            mx = __shfl(mx, 0);
            float e = (lane < 50) ? __expf(x - mx) : 0.f;
            float s = e;
            for (int off = 32; off > 0; off >>= 1) s += __shfl_down(s, off);
            s = __shfl(s, 0);
            if (lane < 50) dots[lane] = e / s;
        }
        __syncthreads();
        const float* R1 = reps + ((size_t)(hop + 1) * 1600 + b * 50) * 300;
        for (int d = tid; d < 300; d += 256) {
            float s = 0.f;
            for (int n = 0; n < 50; ++n) s += dots[n] * R1[(size_t)n * 300 + d];
            u_l[d] += s;
        }
        __syncthreads();
    }
    float acc = 0.f;
    for (int d = tid; d < 300; d += 256) acc += u_l[d] * Wout[d];
    for (int off = 32; off > 0; off >>= 1) acc += __shfl_down(acc, off);
    if (lane == 0) red[wave] = acc;
    __syncthreads();
    if (tid == 0) {
        float s = red[0] + red[1] + red[2] + red[3] + bout[0];
        out[b] = 1.f / (1.f + __expf(-s));
    }
}

// ---------- launch ----------
extern "C" void kernel_launch(void* const* d_in, const int* in_sizes, int n_in,
                              void* d_out, int out_size, void* d_ws, size_t ws_size,
                              hipStream_t stream) {
    (void)in_sizes; (void)n_in; (void)out_size;
    const int*   tc   = (const int*)d_in[0];
    const int*   uh   = (const int*)d_in[1];
    const float* E    = (const float*)d_in[2];
    const float* AWih = (const float*)d_in[3];
    const float* AWhh = (const float*)d_in[4];
    const float* Abih = (const float*)d_in[5];
    const float* Abhh = (const float*)d_in[6];
    const float* CWih = (const float*)d_in[7];
    const float* CWhh = (const float*)d_in[8];
    const float* Cbih = (const float*)d_in[9];
    const float* Cbhh = (const float*)d_in[10];
    const float* Wout = (const float*)d_in[11];
    const float* bout = (const float*)d_in[12];
    float* out = (float*)d_out;

    char* ws = (char*)d_ws;
    size_t off = 0;
    auto take = [&](size_t bytes) -> char* {
        char* p = ws + off;
        off = (off + bytes + 255) & ~(size_t)255;
        return p;
    };
    int* lens_s = (int*)take(640 * 4);
    int* lens_h = (int*)take(1600 * 4);
    int* lens_c = (int*)take(32 * 4);
    int* perm_s = (int*)take(640 * 4);
    int* slen_sorted = (int*)take(640 * 4);
    int* perm_h = (int*)take(1600 * 4);
    int* hlen_sorted = (int*)take(1600 * 4);
    ushort_t* packA = (ushort_t*)take((size_t)6 * 570 * 512 * 2);
    ushort_t* packC = (ushort_t*)take((size_t)2 * 570 * 512 * 2);
    float* srep = (float*)take((size_t)640 * 300 * 4);
    float* reps = (float*)take((size_t)3 * 1600 * 300 * 4);
    float* ubuf = (float*)take((size_t)32 * 300 * 4);
    ushort_t* gxc = (ushort_t*)take((size_t)2 * 20 * 38 * 1024);

    // time-chunk size: gx arena = 170 slots x TC x 38 x 2048 B
    // Cap at 8: keeps arena ~106 MB (L3-resident gate reads) and lets the
    // dead-chain chunk skip prune gx work for finished sequences.
    int TC = 1;
    for (int cand = 50; cand >= 1; --cand) {
        size_t need = off + (size_t)170 * cand * 38 * 2048 + 1024;
        if (need <= ws_size) { TC = cand; break; }
    }
    if (TC > 8) TC = 8;
    ushort_t* gx = (ushort_t*)take((size_t)170 * TC * 38 * 2048);
    int nchunks = (50 + TC - 1) / TC;

    k_lens<<<9, 256, 0, stream>>>(tc, uh, lens_s, lens_h, lens_c);
    k_sort<<<3, 256, 0, stream>>>(lens_s, 640, perm_s, slen_sorted);
    k_sort<<<7, 256, 0, stream>>>(lens_h, 1600, perm_h, hlen_sorted);
    k_packA<<<3420, 64, 0, stream>>>(AWih, AWhh, Abih, Abhh, packA);
    k_packC<<<1140, 64, 0, stream>>>(CWih, CWhh, Cbih, Cbhh, packC);

    {
        void* args[] = { (void*)&tc, (void*)&uh, (void*)&E,
                         (void*)&perm_s, (void*)&slen_sorted,
                         (void*)&perm_h, (void*)&hlen_sorted,
                         (void*)&packA, (void*)&gx, (void*)&srep, (void*)&reps,
                         (void*)&TC, (void*)&nchunks };
        hipLaunchCooperativeKernel((const void*)k_main, dim3(256), dim3(256),
                                   args, 0, stream);
    }

    k_gxc<<<dim3(3, 2, 19), 256, 0, stream>>>(srep, tc, lens_c, packC, gxc);
    k_rec_c<<<2, 256, 0, stream>>>(gxc, lens_c, packC, ubuf);
    k_attn<<<32, 256, 0, stream>>>(reps, ubuf, Wout, bout, out);
}

// Round 6
// 2054.703 us; speedup vs baseline: 1.2842x; 1.0103x over previous
//
#include <hip/hip_runtime.h>
#include <hip/hip_cooperative_groups.h>

typedef short v8s __attribute__((ext_vector_type(8)));
typedef float v4f __attribute__((ext_vector_type(4)));
typedef unsigned short ushort_t;
typedef unsigned int uint_t;

namespace cg = cooperative_groups;

// ---------- helpers ----------
__device__ inline ushort_t f2bf(float f) {
    union { float f; uint_t u; } v; v.f = f;
    uint_t r = v.u + 0x7FFFu + ((v.u >> 16) & 1u);   // RNE
    return (ushort_t)(r >> 16);
}
__device__ inline float bf2f(ushort_t h) {
    union { uint_t u; float f; } v; v.u = ((uint_t)h) << 16;
    return v.f;
}
__device__ inline float sigf(float x) { return 1.f / (1.f + __expf(-x)); }
__device__ inline float tanh_f(float x) {
    float e = __expf(-2.f * x);
    return (1.f - e) / (1.f + e);
}

// ---------- lengths ----------
__global__ void k_lens(const int* __restrict__ tc, const int* __restrict__ uh,
                       int* lens_s, int* lens_h, int* lens_c) {
    int t = blockIdx.x * 256 + threadIdx.x;
    if (t < 640) {
        int c = 0;
        for (int s = 0; s < 50; ++s) c += (tc[t * 53 + 3 + s] != 0);
        lens_s[t] = c;
    } else if (t < 2240) {
        int r = t - 640; int c = 0;
        for (int s = 0; s < 50; ++s) c += (uh[r * 50 + s] != 0);
        lens_h[r] = c;
    } else if (t < 2272) {
        int b = t - 2240; int c = 0;
        for (int tt = 0; tt < 20; ++tt) c += (tc[(b * 20 + tt) * 53 + 3] != 0);
        lens_c[b] = c;
    }
}

// ---------- sort by length descending (brute-force rank, multi-block) ----------
__global__ void k_sort(const int* __restrict__ lens, int n,
                       int* __restrict__ perm, int* __restrict__ slen) {
    int i = blockIdx.x * 256 + threadIdx.x;
    if (i >= n) return;
    int li = lens[i]; int r = 0;
    for (int j = 0; j < n; ++j) {
        int lj = lens[j];
        r += (lj > li) || (lj == li && j < i);
    }
    perm[r] = i; slen[r] = li;
}

// ---------- pack A weights, gate-interleaved: n' = d*4 + gate ----------
// K layout: [0..299]=Wih, [300]=bih+bhh, [301..319]=0, [320..469]=Whh, [470..479]=0
__global__ void k_packA(const float* __restrict__ Wih, const float* __restrict__ Whh,
                        const float* __restrict__ bih, const float* __restrict__ bhh,
                        ushort_t* __restrict__ pack) {
    int job = blockIdx.x; int lane = threadIdx.x;
    int set = job / 570; int rem = job % 570; int tile = rem / 15; int kc = rem % 15;
    int np = tile * 16 + (lane & 15);
    int g = np & 3, d = np >> 2;
    int orig = g * 150 + d;
    int kbase = kc * 32 + (lane >> 4) * 8;
    ushort_t v[8];
#pragma unroll
    for (int j = 0; j < 8; ++j) {
        int k = kbase + j; float f = 0.f;
        if (np < 600) {
            if (k < 300) f = Wih[((size_t)set * 600 + orig) * 300 + k];
            else if (k == 300) f = bih[set * 600 + orig] + bhh[set * 600 + orig];
            else if (k >= 320 && k < 470) f = Whh[((size_t)set * 600 + orig) * 150 + (k - 320)];
        }
        v[j] = f2bf(f);
    }
    uint4 u;
    u.x = (uint_t)v[0] | ((uint_t)v[1] << 16);
    u.y = (uint_t)v[2] | ((uint_t)v[3] << 16);
    u.z = (uint_t)v[4] | ((uint_t)v[5] << 16);
    u.w = (uint_t)v[6] | ((uint_t)v[7] << 16);
    *(uint4*)(pack + ((size_t)job * 64 + lane) * 8) = u;
}

// ---------- pack C weights (Din=303, bias at k=303) ----------
__global__ void k_packC(const float* __restrict__ Wih, const float* __restrict__ Whh,
                        const float* __restrict__ bih, const float* __restrict__ bhh,
                        ushort_t* __restrict__ pack) {
    int job = blockIdx.x; int lane = threadIdx.x;
    int dir = job / 570; int rem = job % 570; int tile = rem / 15; int kc = rem % 15;
    int np = tile * 16 + (lane & 15);
    int g = np & 3, d = np >> 2;
    int orig = g * 150 + d;
    int kbase = kc * 32 + (lane >> 4) * 8;
    ushort_t v[8];
#pragma unroll
    for (int j = 0; j < 8; ++j) {
        int k = kbase + j; float f = 0.f;
        if (np < 600) {
            if (k < 303) f = Wih[((size_t)dir * 600 + orig) * 303 + k];
            else if (k == 303) f = bih[dir * 600 + orig] + bhh[dir * 600 + orig];
            else if (k >= 320 && k < 470) f = Whh[((size_t)dir * 600 + orig) * 150 + (k - 320)];
        }
        v[j] = f2bf(f);
    }
    uint4 u;
    u.x = (uint_t)v[0] | ((uint_t)v[1] << 16);
    u.y = (uint_t)v[2] | ((uint_t)v[3] << 16);
    u.z = (uint_t)v[4] | ((uint_t)v[5] << 16);
    u.w = (uint_t)v[6] | ((uint_t)v[7] << 16);
    *(uint4*)(pack + ((size_t)job * 64 + lane) * 8) = u;
}

// =====================================================================
// Persistent cooperative kernel: alternate [gx GEMM phase] / [rec phase]
// grid = 256 blocks x 512 threads (8 waves -> 2 waves/SIMD, 1 block/CU).
// Co-residency: 8 waves x 256 VGPR = 2048/CU pool; LDS 56KB < 160KB.
// gx phase: job covers 4 timesteps; two waves per timestep
//           (lt = sb*4 + (w>>1)), each wave owns m-half mh = (w&1)*2.
// rec phase: wave w owns tn = w + 8*j (j<5) -> 5 j-bodies/step (was 10),
//           with ping-pong streamed Whh + gate prefetch.
// grpjob/bid 0..169:  <20 -> s (2 dirs x 10 seqblks of 64), else h (6 x 25)
// gx arena layout: slot=grpjob: [lt<TC][tn<38][m<64][l16<16] ushort
// =====================================================================
__launch_bounds__(512, 2)
__global__ void k_main(const int* __restrict__ tcg, const int* __restrict__ uhg,
                       const float* __restrict__ E,
                       const int* __restrict__ perm_s, const int* __restrict__ slen_s,
                       const int* __restrict__ perm_h, const int* __restrict__ hlen_s,
                       const ushort_t* __restrict__ packA,
                       ushort_t* __restrict__ gx,
                       float* __restrict__ srep, float* __restrict__ reps,
                       int TC, int nchunks) {
    const int bid = blockIdx.x;
    const int tid = threadIdx.x;
    const int lane = tid & 63, w = tid >> 6, q = lane >> 4, l16 = lane & 15;

    __shared__ ushort_t H[64][168];
    __shared__ __align__(16) float Gp[8][16][68];

    // ---- rec-role decode (bid < 170) ----
    const int isrec = (bid < 170);
    int r_pos0 = 0, r_windex = 0, r_dir = 0;
    const int* r_lenv = slen_s; const int* r_permv = perm_s;
    float* r_outp = srep;
    if (isrec) {
        if (bid < 20) {
            int grp = bid / 10; r_dir = grp; r_windex = grp; r_pos0 = (bid % 10) * 64;
            r_lenv = slen_s; r_permv = perm_s; r_outp = srep;
        } else {
            int gh = (bid - 20) / 25; r_windex = gh; r_dir = gh & 1;
            r_pos0 = ((bid - 20) % 25) * 64;
            r_lenv = hlen_s; r_permv = perm_h;
            r_outp = reps + (size_t)(gh >> 1) * 1600 * 300;
        }
        for (int i = tid; i < 64 * 84; i += 512) ((uint_t*)H)[i] = 0u;
    }
    int len4[4];
    if (isrec) {
#pragma unroll
        for (int i = 0; i < 4; ++i) len4[i] = r_lenv[r_pos0 + l16 + 16 * i];
    }
    float cst[5][4];
#pragma unroll
    for (int j = 0; j < 5; ++j)
#pragma unroll
        for (int i = 0; i < 4; ++i) cst[j][i] = 0.f;

    cg::grid_group grid = cg::this_grid();

    for (int c = 0; c < nchunks; ++c) {
        const int tcs0 = 50 - c * TC;
        const int tcs = tcs0 < TC ? tcs0 : TC;
        // ================= gx producer phase =================
        {
            const int nstepblk = (tcs + 3) / 4;
            const int njobs = 170 * nstepblk;
            for (int job = bid; job < njobs; job += 256) {
                int gj = job % 170; int sb = job / 170;
                const int* lenv; const int* permv; int pos0, windex, dir, isS;
                if (gj < 20) {
                    int grp = gj / 10; dir = grp; windex = grp; pos0 = (gj % 10) * 64;
                    lenv = slen_s; permv = perm_s; isS = 1;
                } else {
                    int gh = (gj - 20) / 25; windex = gh; dir = gh & 1;
                    pos0 = ((gj - 20) % 25) * 64;
                    lenv = hlen_s; permv = perm_h; isS = 0;
                }
                if (lenv[pos0] <= c * TC) continue;   // sorted desc => block dead
                int lt = sb * 4 + (w >> 1);
                if (lt >= tcs) continue;              // wave-level, no barriers here
                int t = c * TC + lt;
                const int mh = (w & 1) * 2;           // this wave's m-group half

                // ---- A fragments: direct E gather, fp32->bf16 (2 m-groups) ----
                v8s a[2][10];
#pragma unroll
                for (int mg = 0; mg < 2; ++mg) {
                    int pos = pos0 + (mh + mg) * 16 + l16;
                    int len = lenv[pos];
                    int tau = dir ? (len - 1 - t) : t;
                    tau = tau < 0 ? 0 : (tau > 49 ? 49 : tau);
                    int orig = permv[pos];
                    int tok = isS ? tcg[orig * 53 + 3 + tau] : uhg[orig * 50 + tau];
                    const float* Er = E + (size_t)tok * 300;
#pragma unroll
                    for (int kc = 0; kc < 9; ++kc) {
                        int k0 = kc * 32 + q * 8;
                        float4 f0 = *(const float4*)(Er + k0);
                        float4 f1 = *(const float4*)(Er + k0 + 4);
                        v8s r;
                        r[0] = (short)f2bf(f0.x); r[1] = (short)f2bf(f0.y);
                        r[2] = (short)f2bf(f0.z); r[3] = (short)f2bf(f0.w);
                        r[4] = (short)f2bf(f1.x); r[5] = (short)f2bf(f1.y);
                        r[6] = (short)f2bf(f1.z); r[7] = (short)f2bf(f1.w);
                        a[mg][kc] = r;
                    }
                    {   // kc = 9: k = 288 + q*8 + j ; col 300 = 1.0 (bias), >300 = 0
                        v8s r = (v8s){0,0,0,0,0,0,0,0};
                        if (q == 0) {
                            float4 f0 = *(const float4*)(Er + 288);
                            float4 f1 = *(const float4*)(Er + 292);
                            r[0] = (short)f2bf(f0.x); r[1] = (short)f2bf(f0.y);
                            r[2] = (short)f2bf(f0.z); r[3] = (short)f2bf(f0.w);
                            r[4] = (short)f2bf(f1.x); r[5] = (short)f2bf(f1.y);
                            r[6] = (short)f2bf(f1.z); r[7] = (short)f2bf(f1.w);
                        } else if (q == 1) {
                            float4 f0 = *(const float4*)(Er + 296);
                            r[0] = (short)f2bf(f0.x); r[1] = (short)f2bf(f0.y);
                            r[2] = (short)f2bf(f0.z); r[3] = (short)f2bf(f0.w);
                            r[4] = (short)0x3F80;   // bias multiplier 1.0
                        }
                        a[mg][9] = r;
                    }
                }

                const ushort_t* W = packA + (size_t)windex * 570 * 512;
                ushort_t* gout = gx + ((size_t)gj * TC + lt) * 38 * 1024;

                v8s bA[10], bB[10];
                auto loadB = [&](v8s* dst, int tn) {
                    const ushort_t* p = W + (size_t)tn * 15 * 512 + lane * 8;
#pragma unroll
                    for (int kc = 0; kc < 10; ++kc) dst[kc] = *(const v8s*)(p + (size_t)kc * 512);
                };
                auto compute = [&](int tn, v8s* b) {
                    v4f acc[2];
#pragma unroll
                    for (int mg = 0; mg < 2; ++mg) acc[mg] = (v4f){0.f, 0.f, 0.f, 0.f};
#pragma unroll
                    for (int kc = 0; kc < 10; ++kc)
#pragma unroll
                        for (int mg = 0; mg < 2; ++mg)
                            acc[mg] = __builtin_amdgcn_mfma_f32_16x16x32_bf16(a[mg][kc], b[kc], acc[mg], 0, 0, 0);
                    ushort_t* gt = gout + tn * 1024 + l16;
#pragma unroll
                    for (int mg = 0; mg < 2; ++mg)
#pragma unroll
                        for (int r = 0; r < 4; ++r)
                            gt[((mh + mg) * 16 + q * 4 + r) * 16] = f2bf(acc[mg][r]);
                };
                loadB(bA, 0);
                for (int tn = 0; tn < 38; tn += 2) {
                    loadB(bB, tn + 1 < 38 ? tn + 1 : 37);
                    compute(tn, bA);
                    loadB(bA, tn + 2 < 38 ? tn + 2 : 37);
                    compute(tn + 1, bB);
                }
            }
        }
        grid.sync();
        // ================= recurrence phase =================
        if (isrec) {
            int blockmax = r_lenv[r_pos0];
            int steps = blockmax - c * TC;
            steps = steps < 0 ? 0 : (steps > tcs ? tcs : steps);
            if (steps > 0) {
                const ushort_t* wslot = packA + (size_t)r_windex * 570 * 512;
                const ushort_t* gslot = gx + (size_t)bid * TC * 38 * 1024;
                // streamed Whh fragments (kc 10..14 of the pack), clamped tn
                auto loadW = [&](int j, v8s (&dst)[5]) {
                    int tn = w + 8 * j; int tnc = tn > 37 ? 37 : tn;
                    const ushort_t* wp = wslot + (size_t)tnc * 15 * 512 + lane * 8;
#pragma unroll
                    for (int kc = 0; kc < 5; ++kc) dst[kc] = *(const v8s*)(wp + (size_t)(10 + kc) * 512);
                };
                for (int lt = 0; lt < steps; ++lt) {
                    int t = c * TC + lt;
                    const ushort_t* gstep = gslot + (size_t)lt * 38 * 1024;
                    auto loadG = [&](int j, ushort4 (&dst)[4]) {
                        int tn = w + 8 * j; int tnc = tn > 37 ? 37 : tn;
                        const ushort_t* gb = gstep + (size_t)tnc * 1024 + q * 4;
#pragma unroll
                        for (int i = 0; i < 4; ++i)
                            dst[i] = *(const ushort4*)(gb + (l16 + 16 * i) * 16);
                    };
                    v8s wbA[5], wbB[5];
                    ushort4 gqA[4], gqB[4];
                    // issue j=0 loads before the barrier: independent of H
                    loadW(0, wbA); loadG(0, gqA);
                    __syncthreads();   // prior-step H writes visible
                    v8s ah[4][5];
#pragma unroll
                    for (int mtg = 0; mtg < 4; ++mtg)
#pragma unroll
                        for (int kc = 0; kc < 5; ++kc)
                            ah[mtg][kc] = *(const v8s*)&H[mtg * 16 + l16][kc * 32 + q * 8];
                    __syncthreads();   // ah loaded; H writable
                    auto jbody = [&](int j, v8s (&wcur)[5], ushort4 (&gcur)[4],
                                     v8s (&wnxt)[5], ushort4 (&gnxt)[4]) {
                        if (j < 4) { loadW(j + 1, wnxt); loadG(j + 1, gnxt); }
                        int tn = w + 8 * j;
                        if (tn < 38) {
                            v4f acc[4];
#pragma unroll
                            for (int mtg = 0; mtg < 4; ++mtg) acc[mtg] = (v4f){0.f, 0.f, 0.f, 0.f};
#pragma unroll
                            for (int kc = 0; kc < 5; ++kc)
#pragma unroll
                                for (int mtg = 0; mtg < 4; ++mtg)
                                    acc[mtg] = __builtin_amdgcn_mfma_f32_16x16x32_bf16(ah[mtg][kc], wcur[kc], acc[mtg], 0, 0, 0);
#pragma unroll
                            for (int mtg = 0; mtg < 4; ++mtg)
                                *(v4f*)&Gp[w][l16][mtg * 16 + q * 4] = acc[mtg];
                            int d = 4 * tn + q;
#pragma unroll
                            for (int i = 0; i < 4; ++i) {
                                int m = l16 + 16 * i;
                                if (t < len4[i]) {
                                    float gi = bf2f(gcur[i].x) + Gp[w][q * 4 + 0][m];
                                    float gf = bf2f(gcur[i].y) + Gp[w][q * 4 + 1][m];
                                    float gg = bf2f(gcur[i].z) + Gp[w][q * 4 + 2][m];
                                    float go = bf2f(gcur[i].w) + Gp[w][q * 4 + 3][m];
                                    float cn = sigf(gf) * cst[j][i] + sigf(gi) * tanh_f(gg);
                                    cst[j][i] = cn;
                                    if (d < 150) H[m][d] = f2bf(sigf(go) * tanh_f(cn));
                                }
                            }
                        }
                    };
                    jbody(0, wbA, gqA, wbB, gqB);
                    jbody(1, wbB, gqB, wbA, gqA);
                    jbody(2, wbA, gqA, wbB, gqB);
                    jbody(3, wbB, gqB, wbA, gqA);
                    jbody(4, wbA, gqA, wbB, gqB);
                }
                __syncthreads();
            }
        }
        grid.sync();
    }
    // ---- final outputs ----
    if (isrec) {
        int m = tid >> 3, dc = tid & 7;
        int orig = r_permv[r_pos0 + m];
#pragma unroll
        for (int k = 0; k < 19; ++k) {
            int d = dc + 8 * k;
            if (d < 150) r_outp[(size_t)orig * 300 + r_dir * 150 + d] = bf2f(H[m][d]);
        }
    }
}

// ---------- C-LSTM x-projection GEMM (split over tn via blockIdx.z) ----------
// rows per dir: R = b*20 + t (consumption step t); A source te = dir? clen-1-t : t
// gxc layout: [dir][t][tn][b<32][l16<16] ushort
__launch_bounds__(256, 1)
__global__ void k_gxc(const float* __restrict__ srep, const int* __restrict__ tcg,
                      const int* __restrict__ lens_c, const ushort_t* __restrict__ packC,
                      ushort_t* __restrict__ gxc) {
    const int dir = blockIdx.y;
    const int R0 = blockIdx.x * 256;
    const int tnbase = blockIdx.z * 2;
    const int tid = threadIdx.x, lane = tid & 63, w = tid >> 6, q = lane >> 4, l16 = lane & 15;

    v8s a[4][10];
#pragma unroll
    for (int mtg = 0; mtg < 4; ++mtg) {
        int R = R0 + w * 64 + mtg * 16 + l16;
        R = R < 639 ? R : 639;
        int b = R / 20, t = R % 20;
        int clen = lens_c[b];
        int te = dir ? (clen - 1 - t) : t;
        te = te < 0 ? 0 : (te > 19 ? 19 : te);
        const float* sr = srep + (size_t)(b * 20 + te) * 300;
        const int* ft = tcg + (size_t)(b * 20 + te) * 53;
#pragma unroll
        for (int kc = 0; kc < 9; ++kc) {
            int k0 = kc * 32 + q * 8;
            float4 f0 = *(const float4*)(sr + k0);
            float4 f1 = *(const float4*)(sr + k0 + 4);
            v8s r;
            r[0] = (short)f2bf(f0.x); r[1] = (short)f2bf(f0.y);
            r[2] = (short)f2bf(f0.z); r[3] = (short)f2bf(f0.w);
            r[4] = (short)f2bf(f1.x); r[5] = (short)f2bf(f1.y);
            r[6] = (short)f2bf(f1.z); r[7] = (short)f2bf(f1.w);
            a[mtg][kc] = r;
        }
        {   // kc=9: k = 288+q*8+j; 300..302 = feats, 303 = 1.0
            v8s r = (v8s){0,0,0,0,0,0,0,0};
            if (q == 0) {
                float4 f0 = *(const float4*)(sr + 288);
                float4 f1 = *(const float4*)(sr + 292);
                r[0] = (short)f2bf(f0.x); r[1] = (short)f2bf(f0.y);
                r[2] = (short)f2bf(f0.z); r[3] = (short)f2bf(f0.w);
                r[4] = (short)f2bf(f1.x); r[5] = (short)f2bf(f1.y);
                r[6] = (short)f2bf(f1.z); r[7] = (short)f2bf(f1.w);
            } else if (q == 1) {
                float4 f0 = *(const float4*)(sr + 296);
                r[0] = (short)f2bf(f0.x); r[1] = (short)f2bf(f0.y);
                r[2] = (short)f2bf(f0.z); r[3] = (short)f2bf(f0.w);
                r[4] = (short)f2bf((float)ft[0]);
                r[5] = (short)f2bf((float)ft[1]);
                r[6] = (short)f2bf((float)ft[2]);
                r[7] = (short)0x3F80;
            }
            a[mtg][9] = r;
        }
    }
    const ushort_t* W = packC + (size_t)dir * 570 * 512;
    v8s bA[10];
    auto loadB = [&](v8s* dst, int tn) {
        const ushort_t* p = W + (size_t)tn * 15 * 512 + lane * 8;
#pragma unroll
        for (int kc = 0; kc < 10; ++kc) dst[kc] = *(const v8s*)(p + (size_t)kc * 512);
    };
    auto compute = [&](int tn, v8s* b) {
        v4f acc[4];
#pragma unroll
        for (int mtg = 0; mtg < 4; ++mtg) acc[mtg] = (v4f){0.f, 0.f, 0.f, 0.f};
#pragma unroll
        for (int kc = 0; kc < 10; ++kc)
#pragma unroll
            for (int mtg = 0; mtg < 4; ++mtg)
                acc[mtg] = __builtin_amdgcn_mfma_f32_16x16x32_bf16(a[mtg][kc], b[kc], acc[mtg], 0, 0, 0);
#pragma unroll
        for (int mtg = 0; mtg < 4; ++mtg)
#pragma unroll
            for (int r = 0; r < 4; ++r) {
                int R = R0 + w * 64 + mtg * 16 + q * 4 + r;
                if (R < 640) {
                    int b = R / 20, t = R % 20;
                    gxc[(((size_t)(dir * 20 + t) * 38 + tn) << 9) + b * 16 + l16] = f2bf(acc[mtg][r]);
                }
            }
    };
    for (int tn = tnbase; tn < tnbase + 2; ++tn) {
        loadB(bA, tn);
        compute(tn, bA);
    }
}

// ---------- conversation-level recurrence: register Whh, M=32 ----------
__launch_bounds__(256, 1)
__global__ void k_rec_c(const ushort_t* __restrict__ gxc, const int* __restrict__ lens_c,
                        const ushort_t* __restrict__ packC, float* __restrict__ out) {
    const int dir = blockIdx.x;
    const int tid = threadIdx.x, lane = tid & 63, w = tid >> 6, q = lane >> 4, l16 = lane & 15;

    __shared__ ushort_t H[32][168];
    __shared__ __align__(16) float Gp[4][16][68];
    __shared__ int lensl[32];
    __shared__ int mxs;

    if (tid < 32) lensl[tid] = lens_c[tid];
    for (int i = tid; i < 32 * 84; i += 256) ((uint_t*)H)[i] = 0u;
    __syncthreads();
    if (tid == 0) {
        int mx = 0;
        for (int i = 0; i < 32; ++i) mx = max(mx, lensl[i]);
        mxs = mx;
    }
    __syncthreads();
    const int maxlen = mxs;
    int len2[2];
#pragma unroll
    for (int i = 0; i < 2; ++i) len2[i] = lensl[i * 16 + l16];

    v8s wb[10][5];
#pragma unroll
    for (int j = 0; j < 10; ++j) {
        int tn = w + 4 * j; int tnc = tn > 37 ? 37 : tn;
        const ushort_t* wp = packC + (size_t)dir * 570 * 512 + (size_t)tnc * 15 * 512 + lane * 8;
#pragma unroll
        for (int kc = 0; kc < 5; ++kc) wb[j][kc] = *(const v8s*)(wp + (size_t)(10 + kc) * 512);
    }
    float cst[10][2];
#pragma unroll
    for (int j = 0; j < 10; ++j)
#pragma unroll
        for (int i = 0; i < 2; ++i) cst[j][i] = 0.f;

    for (int t = 0; t < maxlen; ++t) {
        __syncthreads();
        v8s ah[2][5];
#pragma unroll
        for (int mtg = 0; mtg < 2; ++mtg)
#pragma unroll
            for (int kc = 0; kc < 5; ++kc)
                ah[mtg][kc] = *(const v8s*)&H[mtg * 16 + l16][kc * 32 + q * 8];
        __syncthreads();
#pragma unroll
        for (int j = 0; j < 10; ++j) {
            int tn = w + 4 * j;
            if (tn < 38) {
                v4f acc[2];
#pragma unroll
                for (int mtg = 0; mtg < 2; ++mtg) acc[mtg] = (v4f){0.f, 0.f, 0.f, 0.f};
#pragma unroll
                for (int kc = 0; kc < 5; ++kc)
#pragma unroll
                    for (int mtg = 0; mtg < 2; ++mtg)
                        acc[mtg] = __builtin_amdgcn_mfma_f32_16x16x32_bf16(ah[mtg][kc], wb[j][kc], acc[mtg], 0, 0, 0);
#pragma unroll
                for (int mtg = 0; mtg < 2; ++mtg)
                    *(v4f*)&Gp[w][l16][mtg * 16 + q * 4] = acc[mtg];
                int d = 4 * tn + q;
                const ushort_t* gbase = gxc + (((size_t)(dir * 20 + t) * 38 + tn) << 9) + q * 4;
#pragma unroll
                for (int i = 0; i < 2; ++i) {
                    int m = l16 + 16 * i;
                    if (t < len2[i]) {
                        ushort4 gv = *(const ushort4*)(gbase + m * 16);
                        float gi = bf2f(gv.x) + Gp[w][q * 4 + 0][m];
                        float gf = bf2f(gv.y) + Gp[w][q * 4 + 1][m];
                        float gg = bf2f(gv.z) + Gp[w][q * 4 + 2][m];
                        float go = bf2f(gv.w) + Gp[w][q * 4 + 3][m];
                        float cn = sigf(gf) * cst[j][i] + sigf(gi) * tanh_f(gg);
                        cst[j][i] = cn;
                        if (d < 150) H[m][d] = f2bf(sigf(go) * tanh_f(cn));
                    }
                }
            }
        }
    }
    __syncthreads();
    {
        int m = tid >> 3;
#pragma unroll
        for (int k = 0; k < 19; ++k) {
            int d = (tid & 7) + 8 * k;
            if (d < 150) out[(size_t)m * 300 + dir * 150 + d] = bf2f(H[m][d]);
        }
    }
}

// ---------- attention hops + output ----------
__global__ void k_attn(const float* __restrict__ reps, const float* __restrict__ u_in,
                       const float* __restrict__ Wout, const float* __restrict__ bout,
                       float* __restrict__ out) {
    const int b = blockIdx.x;
    const int tid = threadIdx.x;
    const int wave = tid >> 6, lane = tid & 63;
    __shared__ float u_l[300];
    __shared__ float dots[64];
    __shared__ float red[4];
    for (int d = tid; d < 300; d += 256) u_l[d] = u_in[b * 300 + d];
    __syncthreads();
    for (int hop = 0; hop < 2; ++hop) {
        const float* R0 = reps + ((size_t)hop * 1600 + b * 50) * 300;
        for (int n = wave; n < 50; n += 4) {
            float p = 0.f;
            for (int d = lane; d < 300; d += 64) p += R0[(size_t)n * 300 + d] * u_l[d];
            for (int off = 32; off > 0; off >>= 1) p += __shfl_down(p, off);
            if (lane == 0) dots[n] = p;
        }
        __syncthreads();
        if (tid < 64) {
            float x = (lane < 50) ? dots[lane] : -3.4e38f;
            float mx = x;
            for (int off = 32; off > 0; off >>= 1) mx = fmaxf(mx, __shfl_down(mx, off));
            mx = __shfl(mx, 0);
            float e = (lane < 50) ? __expf(x - mx) : 0.f;
            float s = e;
            for (int off = 32; off > 0; off >>= 1) s += __shfl_down(s, off);
            s = __shfl(s, 0);
            if (lane < 50) dots[lane] = e / s;
        }
        __syncthreads();
        const float* R1 = reps + ((size_t)(hop + 1) * 1600 + b * 50) * 300;
        for (int d = tid; d < 300; d += 256) {
            float s = 0.f;
            for (int n = 0; n < 50; ++n) s += dots[n] * R1[(size_t)n * 300 + d];
            u_l[d] += s;
        }
        __syncthreads();
    }
    float acc = 0.f;
    for (int d = tid; d < 300; d += 256) acc += u_l[d] * Wout[d];
    for (int off = 32; off > 0; off >>= 1) acc += __shfl_down(acc, off);
    if (lane == 0) red[wave] = acc;
    __syncthreads();
    if (tid == 0) {
        float s = red[0] + red[1] + red[2] + red[3] + bout[0];
        out[b] = 1.f / (1.f + __expf(-s));
    }
}

// ---------- launch ----------
extern "C" void kernel_launch(void* const* d_in, const int* in_sizes, int n_in,
                              void* d_out, int out_size, void* d_ws, size_t ws_size,
                              hipStream_t stream) {
    (void)in_sizes; (void)n_in; (void)out_size;
    const int*   tc   = (const int*)d_in[0];
    const int*   uh   = (const int*)d_in[1];
    const float* E    = (const float*)d_in[2];
    const float* AWih = (const float*)d_in[3];
    const float* AWhh = (const float*)d_in[4];
    const float* Abih = (const float*)d_in[5];
    const float* Abhh = (const float*)d_in[6];
    const float* CWih = (const float*)d_in[7];
    const float* CWhh = (const float*)d_in[8];
    const float* Cbih = (const float*)d_in[9];
    const float* Cbhh = (const float*)d_in[10];
    const float* Wout = (const float*)d_in[11];
    const float* bout = (const float*)d_in[12];
    float* out = (float*)d_out;

    char* ws = (char*)d_ws;
    size_t off = 0;
    auto take = [&](size_t bytes) -> char* {
        char* p = ws + off;
        off = (off + bytes + 255) & ~(size_t)255;
        return p;
    };
    int* lens_s = (int*)take(640 * 4);
    int* lens_h = (int*)take(1600 * 4);
    int* lens_c = (int*)take(32 * 4);
    int* perm_s = (int*)take(640 * 4);
    int* slen_sorted = (int*)take(640 * 4);
    int* perm_h = (int*)take(1600 * 4);
    int* hlen_sorted = (int*)take(1600 * 4);
    ushort_t* packA = (ushort_t*)take((size_t)6 * 570 * 512 * 2);
    ushort_t* packC = (ushort_t*)take((size_t)2 * 570 * 512 * 2);
    float* srep = (float*)take((size_t)640 * 300 * 4);
    float* reps = (float*)take((size_t)3 * 1600 * 300 * 4);
    float* ubuf = (float*)take((size_t)32 * 300 * 4);
    ushort_t* gxc = (ushort_t*)take((size_t)2 * 20 * 38 * 1024);

    // time-chunk size: gx arena = 170 slots x TC x 38 x 2048 B
    // Cap at 8: keeps arena ~106 MB (L3-resident gate reads) and lets the
    // dead-chain chunk skip prune gx work for finished sequences.
    int TC = 1;
    for (int cand = 50; cand >= 1; --cand) {
        size_t need = off + (size_t)170 * cand * 38 * 2048 + 1024;
        if (need <= ws_size) { TC = cand; break; }
    }
    if (TC > 8) TC = 8;
    ushort_t* gx = (ushort_t*)take((size_t)170 * TC * 38 * 2048);
    int nchunks = (50 + TC - 1) / TC;

    k_lens<<<9, 256, 0, stream>>>(tc, uh, lens_s, lens_h, lens_c);
    k_sort<<<3, 256, 0, stream>>>(lens_s, 640, perm_s, slen_sorted);
    k_sort<<<7, 256, 0, stream>>>(lens_h, 1600, perm_h, hlen_sorted);
    k_packA<<<3420, 64, 0, stream>>>(AWih, AWhh, Abih, Abhh, packA);
    k_packC<<<1140, 64, 0, stream>>>(CWih, CWhh, Cbih, Cbhh, packC);

    {
        void* args[] = { (void*)&tc, (void*)&uh, (void*)&E,
                         (void*)&perm_s, (void*)&slen_sorted,
                         (void*)&perm_h, (void*)&hlen_sorted,
                         (void*)&packA, (void*)&gx, (void*)&srep, (void*)&reps,
                         (void*)&TC, (void*)&nchunks };
        hipLaunchCooperativeKernel((const void*)k_main, dim3(256), dim3(512),
                                   args, 0, stream);
    }

    k_gxc<<<dim3(3, 2, 19), 256, 0, stream>>>(srep, tc, lens_c, packC, gxc);
    k_rec_c<<<2, 256, 0, stream>>>(gxc, lens_c, packC, ubuf);
    k_attn<<<32, 256, 0, stream>>>(reps, ubuf, Wout, bout, out);
}